// Round 14
// baseline (188.972 us; speedup 1.0000x reference)
//
#include <hip/hip_runtime.h>
#include <hip/hip_fp16.h>

#define D_DIM 256
#define K_CODES 1024
#define MARGIN 6e-4f
#define RCAP 48

typedef __attribute__((ext_vector_type(8))) _Float16 half8;
typedef __attribute__((ext_vector_type(4))) float f32x4;

// RNE f32 -> fp16 bits (validated r12/r13)
__device__ __forceinline__ unsigned short f2h(float x) {
    __half h = __float2half(x);
    return *reinterpret_cast<unsigned short*>(&h);
}
__device__ __forceinline__ void gload16(const void* g, void* l) {
    __builtin_amdgcn_global_load_lds(
        (const __attribute__((address_space(1))) void*)g,
        (__attribute__((address_space(3))) void*)l, 16, 0, 0);
}

// ---------------------------------------------------------------------------
// k_prep: [0,128) z2 | [128,132) e2 | [132,2180) z fp16 transpose+swz |
//         [2180,2196) e fp16 swz | [2196,2228) rowCnt zero (+lossAcc)
// (unchanged from validated rounds 12/13)
// ---------------------------------------------------------------------------
__global__ __launch_bounds__(256) void k_prep(const float* __restrict__ z,
                                              const float* __restrict__ e,
                                              float* __restrict__ z2,
                                              float* __restrict__ e2,
                                              unsigned short* __restrict__ zh,
                                              unsigned short* __restrict__ eh,
                                              int* __restrict__ rowCnt,
                                              float* __restrict__ lossAcc) {
    __shared__ float tile[64][65];
    const int bi = blockIdx.x;
    const int t  = threadIdx.x;
    if (bi < 128) {                    // ---- z2 ----
        int n = bi * 256 + t;
        int b = n >> 10, nl = n & 1023;
        const float* p = z + (size_t)b * (D_DIM * 1024) + nl;
        float s = 0.f;
#pragma unroll 8
        for (int d = 0; d < D_DIM; ++d) {
            float v = p[(size_t)d * 1024];
            s = fmaf(v, v, s);
        }
        z2[n] = s;
    } else if (bi < 132) {             // ---- e2 ----
        int k = (bi - 128) * 256 + t;
        const float4* p = (const float4*)(e + (size_t)k * D_DIM);
        float s = 0.f;
#pragma unroll 4
        for (int c = 0; c < D_DIM / 4; ++c) {
            float4 v = p[c];
            s = fmaf(v.x, v.x, s); s = fmaf(v.y, v.y, s);
            s = fmaf(v.z, v.z, s); s = fmaf(v.w, v.w, s);
        }
        e2[k] = s;
    } else if (bi < 2180) {            // ---- z fp16 transpose + swizzle ----
        int bb = bi - 132;
        int n0 = (bb & 511) * 64;
        int d0 = (bb >> 9) * 64;
        int b = n0 >> 10, nl0 = n0 & 1023;
#pragma unroll 4
        for (int i = 0; i < 16; ++i) {
            int flat = i * 256 + t;
            int dd = flat >> 6, j = flat & 63;
            tile[dd][j] = z[(size_t)b * (D_DIM * 1024) +
                            (size_t)(d0 + dd) * 1024 + nl0 + j];
        }
        __syncthreads();
#pragma unroll
        for (int i = 0; i < 4; ++i) {
            int flat = i * 256 + t;
            int row = flat >> 4, ch = flat & 15;
            int s8p = ch >> 1, half = ch & 1;
            int s8  = s8p ^ (row & 7);
            int ddl = s8 * 8 + half * 4;
            unsigned int h[4];
#pragma unroll
            for (int m2 = 0; m2 < 4; ++m2)
                h[m2] = f2h(tile[ddl + m2][row]);
            uint2 ph = { h[0] | (h[1] << 16), h[2] | (h[3] << 16) };
            size_t off = (size_t)(n0 + row) * 256 + d0 + s8p * 8 + half * 4;
            *(uint2*)(zh + off) = ph;
        }
    } else if (bi < 2196) {            // ---- e fp16 swizzle ----
        int k0 = (bi - 2180) * 64;
#pragma unroll 4
        for (int i = 0; i < 16; ++i) {
            int flat = i * 256 + t;
            int row = flat >> 6, ch = flat & 63;
            int slab = ch >> 4, s8p = (ch >> 1) & 7, half = ch & 1;
            int s8 = s8p ^ (row & 7);
            int d  = slab * 64 + s8 * 8 + half * 4;
            float4 v = *(const float4*)(e + (size_t)(k0 + row) * 256 + d);
            uint2 ph = { (unsigned)f2h(v.x) | ((unsigned)f2h(v.y) << 16),
                         (unsigned)f2h(v.z) | ((unsigned)f2h(v.w) << 16) };
            size_t off = (size_t)(k0 + row) * 256 + slab * 64 + s8p * 8 + half * 4;
            *(uint2*)(eh + off) = ph;
        }
    } else {                           // ---- rowCnt zero ----
        int bb = bi - 2196;
        if (bb == 0 && t == 0) lossAcc[0] = 0.f;
#pragma unroll
        for (int i = 0; i < 4; ++i)
            rowCnt[bb * 1024 + i * 256 + t] = 0;
    }
}

// ---------------------------------------------------------------------------
// k_score v3: persistent blocks, 512 x 512 thr, A-resident + 32-slab B
// stream (validated round 13; dropped 108 -> ~55 us).
// ---------------------------------------------------------------------------
__global__ __launch_bounds__(512) void k_score(
        const unsigned short* __restrict__ zh,
        const unsigned short* __restrict__ eh,
        const float* __restrict__ e2,
        int* __restrict__ rowCnt, uint2* __restrict__ rowCand) {
    __shared__ unsigned short lds[32768];  // A[0,16384) | B0 | B1

    const int t    = threadIdx.x;          // 0..511
    const int lane = t & 63;
    const int w    = t >> 6;               // 0..7
    const int wr   = w >> 1;               // row-group 0..3
    const int wc   = w & 1;                // code-half 0..1
    const int c    = lane & 15;
    const int kq   = lane >> 4;            // 0..3
    const int n0   = blockIdx.x * 64;

#pragma unroll
    for (int p = 0; p < 4; ++p) {
        int slot = p * 512 + t;
        int row  = slot >> 5, sg = slot & 31;
        gload16(zh + (size_t)(n0 + row) * 256 + sg * 8,
                &lds[(p * 512 + w * 64) * 8]);
    }

#define STAGE_B(S, BUF)                                                      \
    do {                                                                     \
        int kc_ = (S) >> 2, dg_ = (S) & 3;                                   \
        _Pragma("unroll")                                                    \
        for (int p = 0; p < 2; ++p) {                                        \
            int slot = p * 512 + t;                                          \
            int code = slot >> 3, sg = slot & 7;                             \
            gload16(eh + (size_t)(kc_ * 128 + code) * 256 + dg_ * 64 + sg * 8, \
                    &lds[16384 + (BUF) * 8192 + (p * 512 + w * 64) * 8]);    \
        }                                                                    \
    } while (0)

    f32x4 acc[4];
#pragma unroll
    for (int cf = 0; cf < 4; ++cf) acc[cf] = (f32x4){0.f, 0.f, 0.f, 0.f};
    float m_run[4] = { 3.4e38f, 3.4e38f, 3.4e38f, 3.4e38f };

    const int rl = wr * 16 + c;
    STAGE_B(0, 0);
    __syncthreads();

    for (int s = 0; s < 32; ++s) {
        if (s < 31) STAGE_B(s + 1, (s + 1) & 1);
        {
            const int dg = s & 3;
            const unsigned short* Bb = &lds[16384 + (s & 1) * 8192];
#pragma unroll
            for (int ks = 0; ks < 2; ++ks) {
                int wo = ks * 4 + kq;
                half8 a = *(const half8*)&lds[rl * 256 + dg * 64 +
                                              (wo ^ (rl & 7)) * 8];
                half8 b[4];
#pragma unroll
                for (int cf = 0; cf < 4; ++cf) {
                    int cl = wc * 64 + cf * 16 + c;
                    b[cf] = *(const half8*)&Bb[cl * 64 + (wo ^ (cl & 7)) * 8];
                }
#pragma unroll
                for (int cf = 0; cf < 4; ++cf)
                    acc[cf] = __builtin_amdgcn_mfma_f32_16x16x32_f16(
                        a, b[cf], acc[cf], 0, 0, 0);
            }
        }
        if ((s & 3) == 3) {
            const int kc = s >> 2;
            float e2r[4];
#pragma unroll
            for (int cf = 0; cf < 4; ++cf)
                e2r[cf] = e2[kc * 128 + wc * 64 + cf * 16 + c];
            float mnew[4];
#pragma unroll
            for (int reg = 0; reg < 4; ++reg) {
                float mm = 3.4e38f;
#pragma unroll
                for (int cf = 0; cf < 4; ++cf)
                    mm = fminf(mm, fmaf(-2.f, acc[cf][reg], e2r[cf]));
                mnew[reg] = mm;
            }
#pragma unroll
            for (int m = 1; m < 16; m <<= 1)
#pragma unroll
                for (int reg = 0; reg < 4; ++reg)
                    mnew[reg] = fminf(mnew[reg], __shfl_xor(mnew[reg], m, 64));
#pragma unroll
            for (int reg = 0; reg < 4; ++reg)
                mnew[reg] = fminf(mnew[reg], m_run[reg]);
#pragma unroll
            for (int cf = 0; cf < 4; ++cf)
#pragma unroll
                for (int reg = 0; reg < 4; ++reg) {
                    float sv = fmaf(-2.f, acc[cf][reg], e2r[cf]);
                    if (sv <= mnew[reg] + MARGIN) {
                        int n = n0 + wr * 16 + kq * 4 + reg;
                        int k = kc * 128 + wc * 64 + cf * 16 + c;
                        int pos = atomicAdd(&rowCnt[n], 1);
                        if (pos < RCAP) {
                            uint2 cd; cd.x = (unsigned)k;
                            cd.y = __float_as_uint(sv);
                            rowCand[n * RCAP + pos] = cd;
                        }
                    }
                }
#pragma unroll
            for (int reg = 0; reg < 4; ++reg) m_run[reg] = mnew[reg];
#pragma unroll
            for (int cf = 0; cf < 4; ++cf) acc[cf] = (f32x4){0.f, 0.f, 0.f, 0.f};
        }
        __syncthreads();
    }
#undef STAGE_B
}

// ---------------------------------------------------------------------------
// k_select: global-min filter + exact rescore of survivors (validated r10-13).
// ---------------------------------------------------------------------------
__global__ __launch_bounds__(256) void k_select(
        const float* __restrict__ z, const float* __restrict__ e,
        const float* __restrict__ z2a, const float* __restrict__ e2,
        const int* __restrict__ rowCnt, const uint2* __restrict__ rowCand,
        float* __restrict__ outIdx, int* __restrict__ wsIdx) {
    const int t = threadIdx.x, lane = t & 63, w = t >> 6;
    const int wid = blockIdx.x * 4 + w;       // 0..4095
    for (int rr = 0; rr < 8; ++rr) {
        const int n = wid * 8 + rr;
        const int cnt = rowCnt[n];
        const float* zrow = z + (size_t)(n >> 10) * (D_DIM * 1024) + (n & 1023);
        unsigned long long key = 0xFFFFFFFFFFFFFFFFULL;
        if (cnt <= RCAP) {
            float s = 3.4e38f;
            int   k = 0;
            if (lane < cnt) {
                uint2 cd = rowCand[n * RCAP + lane];
                k = (int)cd.x;
                s = __uint_as_float(cd.y);
            }
            float gmin = s;
#pragma unroll
            for (int m = 1; m < 64; m <<= 1)
                gmin = fminf(gmin, __shfl_xor(gmin, m, 64));
            bool surv = (lane < cnt) && (s <= gmin + MARGIN);
            unsigned long long bal = __ballot(surv);
            if (__popcll(bal) == 1) {            // sole survivor == argmin
                if (surv) { outIdx[n] = (float)k; wsIdx[n] = k; }
                continue;                         // bal wave-uniform
            }
            if (surv) {
                const float* er = e + (size_t)k * D_DIM;
                float ze = 0.f;
#pragma unroll 8
                for (int d = 0; d < D_DIM; ++d)
                    ze = fmaf(zrow[(size_t)d * 1024], er[d], ze);
                float t1 = z2a[n] + e2[k];
                float dist = fmaf(-2.f, ze, t1);
                key = ((unsigned long long)__float_as_uint(dist) << 32) |
                      (unsigned int)k;
            }
        } else {                      // deterministic fallback: full scan
            const float z2r = z2a[n];
            for (int j = 0; j < 16; ++j) {
                int k = lane * 16 + j;
                const float* er = e + (size_t)k * D_DIM;
                float ze = 0.f;
#pragma unroll 8
                for (int d = 0; d < D_DIM; ++d)
                    ze = fmaf(zrow[(size_t)d * 1024], er[d], ze);
                float t1 = z2r + e2[k];
                float dist = fmaf(-2.f, ze, t1);
                unsigned long long kk =
                    ((unsigned long long)__float_as_uint(dist) << 32) |
                    (unsigned int)k;
                if (kk < key) key = kk;
            }
        }
#pragma unroll
        for (int m = 1; m < 64; m <<= 1) {
            unsigned long long o = __shfl_xor(key, m, 64);
            if (o < key) key = o;
        }
        if (lane == 0) {
            int k = (int)(unsigned int)(key & 0xFFFFFFFFULL);
            outIdx[n] = (float)k;
            wsIdx[n]  = k;
        }
    }
}

// ---------------------------------------------------------------------------
// k_epilogue v2: vectorized straight-through. Round 13 profile: 60 us at 915
// GB/s, VALUBusy 3% — per-thread 4B loads/stores at 4KB stride (thread=nl,
// loop d) were latency-bound. Now: gathered e rows staged TRANSPOSED in LDS
// (zqT[d][nl], col-swizzled i^(c4&7): unswizzled stores are a 64-way same-
// bank pileup), compute loop is thread=(dg,i4): float4 z load + 4 contiguous
// LDS scalars + float4 out store — 128B contiguous per 8-lane group, 1KB per
// wave-instruction. NUMERICS identical to validated path: df = fl(q-z),
// out = fl(z+df), loss s = fmaf(df,df,s).
// ---------------------------------------------------------------------------
__global__ __launch_bounds__(256) void k_epilogue(const float* __restrict__ z,
                                                  const float* __restrict__ e,
                                                  const int* __restrict__ wsIdx,
                                                  float* __restrict__ outZ,
                                                  float* __restrict__ lossAcc) {
    __shared__ float zqT[256][32];   // [d][col], col = nl_local ^ ((d>>2)&7)
    __shared__ int idxs[32];
    const int t = threadIdx.x;
    const int n0 = blockIdx.x * 32;
    const int b = n0 >> 10, nl0 = n0 & 1023;

    if (t < 32) idxs[t] = wsIdx[n0 + t];
    __syncthreads();

    // gather e[idx] rows -> transposed LDS (coalesced float4 reads of e)
#pragma unroll
    for (int j = 0; j < 8; ++j) {
        int flat = j * 256 + t;
        int i  = flat >> 6;          // row (nl_local) 0..31
        int c4 = flat & 63;          // float4 col in e row
        float4 v = *(const float4*)(e + (size_t)idxs[i] * D_DIM + c4 * 4);
        int col = i ^ (c4 & 7);
        zqT[c4 * 4 + 0][col] = v.x;
        zqT[c4 * 4 + 1][col] = v.y;
        zqT[c4 * 4 + 2][col] = v.z;
        zqT[c4 * 4 + 3][col] = v.w;
    }
    __syncthreads();

    const int dg = t >> 3;           // 0..31
    const int i4 = t & 7;            // nl quad
    const size_t base = (size_t)b * (D_DIM * 1024) + nl0 + i4 * 4;
    float s = 0.f;
#pragma unroll
    for (int j = 0; j < 8; ++j) {
        int d = dg * 8 + j;
        float4 z4 = *(const float4*)(z + base + (size_t)d * 1024);
        int sw = (d >> 2) & 7;
        float q0 = zqT[d][(i4 * 4 + 0) ^ sw];
        float q1 = zqT[d][(i4 * 4 + 1) ^ sw];
        float q2 = zqT[d][(i4 * 4 + 2) ^ sw];
        float q3 = zqT[d][(i4 * 4 + 3) ^ sw];
        float4 o; float df;
        df = q0 - z4.x; s = fmaf(df, df, s); o.x = z4.x + df;
        df = q1 - z4.y; s = fmaf(df, df, s); o.y = z4.y + df;
        df = q2 - z4.z; s = fmaf(df, df, s); o.z = z4.z + df;
        df = q3 - z4.w; s = fmaf(df, df, s); o.w = z4.w + df;
        *(float4*)(outZ + base + (size_t)d * 1024) = o;
    }
#pragma unroll
    for (int off = 32; off > 0; off >>= 1) s += __shfl_down(s, off, 64);
    if ((t & 63) == 0) atomicAdd(lossAcc, s);
}

__global__ void k_final(const float* __restrict__ lossAcc,
                        float* __restrict__ outLoss) {
    float m = lossAcc[0] * (1.0f / 8388608.0f);
    outLoss[0] = m + 0.25f * m;
}

// ---------------------------------------------------------------------------
extern "C" void kernel_launch(void* const* d_in, const int* in_sizes, int n_in,
                              void* d_out, int out_size, void* d_ws, size_t ws_size,
                              hipStream_t stream) {
    const float* z = (const float*)d_in[0];   // (32,256,32,32)
    const float* e = (const float*)d_in[1];   // (1024,256)
    float* out     = (float*)d_out;
    float* outIdx  = out + 8388608;
    float* outLoss = out + 8421376;

    float* z2      = (float*)d_ws;                        // 32768 f
    float* e2      = z2 + 32768;                          // 1024 f
    float* lossAcc = e2 + 1024;                           // 1 f
    int*   rowCnt  = (int*)(lossAcc + 1);                 // 32768 i
    uintptr_t p = (uintptr_t)(rowCnt + 32768);
    p = (p + 255) & ~(uintptr_t)255;
    uint2* rowCand = (uint2*)p;                           // 32768*48 uint2 = 12 MB
    unsigned short* zh = (unsigned short*)(rowCand + 32768 * RCAP); // 16 MB
    unsigned short* eh = zh + 8388608;                    // 512 KB
    int*   wsIdx   = (int*)(eh + 262144);                 // 32768 i

    k_prep<<<2228, 256, 0, stream>>>(z, e, z2, e2, zh, eh, rowCnt, lossAcc);
    k_score<<<512, 512, 0, stream>>>(zh, eh, e2, rowCnt, rowCand);
    k_select<<<1024, 256, 0, stream>>>(z, e, z2, e2, rowCnt, rowCand,
                                       outIdx, wsIdx);
    k_epilogue<<<1024, 256, 0, stream>>>(z, e, wsIdx, out, lossAcc);
    k_final<<<1, 1, 0, stream>>>(lossAcc, outLoss);
}